// Round 4
// baseline (268.042 us; speedup 1.0000x reference)
//
#include <hip/hip_runtime.h>

// Problem constants (B=4, C=256, H=W=56, heads=8)
#define NUM_G 8
#define HD    32
#define LSP   3136            // 56*56 = 49*64
#define BG    32
#define TPB   256
#define LOG2E 1.4426950408889634f

typedef short bf16x8 __attribute__((ext_vector_type(8)));
typedef float f32x4  __attribute__((ext_vector_type(4)));
typedef unsigned uint2v __attribute__((ext_vector_type(2)));
typedef unsigned uint4v __attribute__((ext_vector_type(4)));

union B8 { bf16x8 h; uint4v u; };
union U8 { bf16x8 h; uint2v u[2]; };

#if __has_builtin(__builtin_amdgcn_exp2f)
#define EXP2F __builtin_amdgcn_exp2f
#else
#define EXP2F exp2f
#endif

// pack two f32 -> two bf16 (RNE), low = a, high = b
__device__ __forceinline__ unsigned pk_bf16(float a, float b) {
#if __has_builtin(__builtin_amdgcn_cvt_pk_bf16_f32)
    typedef __bf16 bf16x2_t __attribute__((ext_vector_type(2)));
    bf16x2_t r = __builtin_amdgcn_cvt_pk_bf16_f32(a, b);
    unsigned u; __builtin_memcpy(&u, &r, 4); return u;
#else
    unsigned ua = __float_as_uint(a); ua += 0x7FFFu + ((ua >> 16) & 1u);
    unsigned ub = __float_as_uint(b); ub += 0x7FFFu + ((ub >> 16) & 1u);
    return (ua >> 16) | (ub & 0xFFFF0000u);
#endif
}

__device__ __forceinline__ short f2bf(float f) {
    unsigned u = __float_as_uint(f);
    u += 0x7FFFu + ((u >> 16) & 1u);
    return (short)(u >> 16);
}

__device__ __forceinline__ float bf2f(short s) {
    return __uint_as_float(((unsigned)(unsigned short)s) << 16);
}

// ---------------- Kernel 1: grouped 1x1 conv via MFMA ----------------
__global__ __launch_bounds__(TPB, 4) void qkv_mfma(
    const float* __restrict__ x,
    const float* __restrict__ Wq, const float* __restrict__ bq,
    const float* __restrict__ Wk, const float* __restrict__ bk,
    const float* __restrict__ Wv, const float* __restrict__ bv,
    short* __restrict__ qt, short* __restrict__ kt, short* __restrict__ v)
{
    const int bg = blockIdx.y, gh = bg & (NUM_G - 1);
    const int lane = threadIdx.x & 63, w = threadIdx.x >> 6;
    const int m = lane & 15, g = lane >> 4;

    const float* xb = x + (size_t)bg * HD * LSP;
    short* qtb = qt + (size_t)bg * LSP * HD;
    short* ktb = kt + (size_t)bg * LSP * HD;
    short* vb  = v  + (size_t)bg * HD * LSP;

    B8 wqf[2], wkf[2], wvf[2];
    float bqv[2], bkv[2], bvv[2][4];
#pragma unroll
    for (int h = 0; h < 2; ++h) {
        const int o = 16 * h + m;
        const float* wqp = Wq + (size_t)(gh * HD + o) * HD + 8 * g;
        const float* wkp = Wk + (size_t)(gh * HD + o) * HD + 8 * g;
        const float* wvp = Wv + (size_t)(gh * HD + o) * HD + 8 * g;
#pragma unroll
        for (int p = 0; p < 4; ++p) {
            wqf[h].u[p] = pk_bf16(wqp[2*p] * LOG2E, wqp[2*p+1] * LOG2E); // fold log2e
            wkf[h].u[p] = pk_bf16(wkp[2*p],         wkp[2*p+1]);
            wvf[h].u[p] = pk_bf16(wvp[2*p],         wvp[2*p+1]);
        }
        bqv[h] = bq[gh * HD + o] * LOG2E;
        bkv[h] = bk[gh * HD + o];
#pragma unroll
        for (int r = 0; r < 4; ++r)
            bvv[h][r] = bv[gh * HD + 16 * h + 4 * g + r];
    }

    const int l0 = blockIdx.x * 256 + w * 64;
    const f32x4 zero = {0.f, 0.f, 0.f, 0.f};
#pragma unroll
    for (int c = 0; c < 4; ++c) {
        const int lc = l0 + 16 * c;
        int lrow = lc + m; if (lrow >= LSP) lrow = LSP - 1;
        B8 xf;
#pragma unroll
        for (int p = 0; p < 4; ++p) {
            const float a0 = xb[(size_t)(8*g + 2*p)     * LSP + lrow];
            const float a1 = xb[(size_t)(8*g + 2*p + 1) * LSP + lrow];
            xf.u[p] = pk_bf16(a0, a1);
        }
#pragma unroll
        for (int h = 0; h < 2; ++h) {
            f32x4 cq = __builtin_amdgcn_mfma_f32_16x16x32_bf16(xf.h, wqf[h].h, zero, 0, 0, 0);
            f32x4 ck = __builtin_amdgcn_mfma_f32_16x16x32_bf16(xf.h, wkf[h].h, zero, 0, 0, 0);
            f32x4 cv = __builtin_amdgcn_mfma_f32_16x16x32_bf16(wvf[h].h, xf.h, zero, 0, 0, 0);
            const int lcol = lc + m;
#pragma unroll
            for (int r = 0; r < 4; ++r) {
                const int lr = lc + 4 * g + r;
                if (lr < LSP) {
                    qtb[(size_t)lr * HD + 16 * h + m] = f2bf(cq[r] + bqv[h]);
                    ktb[(size_t)lr * HD + 16 * h + m] = f2bf(ck[r] + bkv[h]);
                }
                if (lcol < LSP)
                    vb[(size_t)(16 * h + 4 * g + r) * LSP + lcol] = f2bf(cv[r] + bvv[h][r]);
            }
        }
    }
}

// ---------------- Kernel 2: Z[j] = sum_k exp2(q'_j . k_k);  v[d,j] *= 1/Z[j] in-place ----------------
__global__ __launch_bounds__(TPB, 4) void z_mfma(
    const short* __restrict__ qt, const short* __restrict__ kt,
    short* __restrict__ v)
{
    const int bg = blockIdx.y;
    const int jb = blockIdx.x * 128;
    const int t = threadIdx.x;
    const int lane = t & 63, w = t >> 6, m = lane & 15, g = lane >> 4;

    const short* qtb = qt + (size_t)bg * LSP * HD;
    const short* ktb = kt + (size_t)bg * LSP * HD;
    short* vb = v + (size_t)bg * HD * LSP;

    bf16x8 aq[8];
#pragma unroll
    for (int jt = 0; jt < 8; ++jt) {
        int row = jb + 16 * jt + m; if (row >= LSP) row = LSP - 1;
        aq[jt] = *(const bf16x8*)(qtb + (size_t)row * HD + 8 * g);
    }

    f32x4 zacc[8];
#pragma unroll
    for (int jt = 0; jt < 8; ++jt) zacc[jt] = (f32x4){0.f, 0.f, 0.f, 0.f};

    const f32x4 zero = {0.f, 0.f, 0.f, 0.f};
    bf16x8 bkf = *(const bf16x8*)(ktb + (size_t)(16 * w + m) * HD + 8 * g);
    for (int it = 0; it < 49; ++it) {
        const bf16x8 bkc = bkf;
        const int nxt = (it + 1 < 49) ? ((it + 1) * 64 + 16 * w + m) : (16 * w + m);
        bkf = *(const bf16x8*)(ktb + (size_t)nxt * HD + 8 * g);
#pragma unroll
        for (int jt = 0; jt < 8; ++jt) {
            f32x4 c = __builtin_amdgcn_mfma_f32_16x16x32_bf16(aq[jt], bkc, zero, 0, 0, 0);
#pragma unroll
            for (int r = 0; r < 4; ++r) zacc[jt][r] += EXP2F(c[r]);
        }
    }

    __shared__ float zl[128];
    if (t < 128) zl[t] = 0.f;
    __syncthreads();
#pragma unroll
    for (int jt = 0; jt < 8; ++jt) {
#pragma unroll
        for (int r = 0; r < 4; ++r) {
            float s = zacc[jt][r];
            s += __shfl_xor(s, 1); s += __shfl_xor(s, 2);
            s += __shfl_xor(s, 4); s += __shfl_xor(s, 8);
            if (m == 0) atomicAdd(&zl[16 * jt + 4 * g + r], s);
        }
    }
    __syncthreads();

    const int jl = (t & 15) * 8;
    const int d0 = t >> 4;
    const int j = jb + jl;
    if (j < LSP) {
        float rzv[8];
#pragma unroll
        for (int e = 0; e < 8; ++e) rzv[e] = 1.0f / zl[jl + e];
#pragma unroll
        for (int hh = 0; hh < 2; ++hh) {
            short* vp = vb + (size_t)(d0 + 16 * hh) * LSP + j;
            bf16x8 vv = *(bf16x8*)vp;
            B8 o;
#pragma unroll
            for (int p = 0; p < 4; ++p)
                o.u[p] = pk_bf16(bf2f(vv[2*p]) * rzv[2*p], bf2f(vv[2*p+1]) * rzv[2*p+1]);
            *(bf16x8*)vp = o.h;
        }
    }
}

// ---------------- Kernel 3: out[d,k] = sum_j exp2(q'_j.k_k) * v'[d,j] + x ----------------
// P transpose through wave-private LDS. Conflict-free scheme (16-lane phase model):
//   column c (=m) at stride 32 dwords; logical dword d stored at d ^ (2c).
//   b64 writes at even d -> banks (d^2m): permutation of evens per phase.
//   Reads as 2x b64 (never b128): banks distinct per 16-lane phase.
__global__ __launch_bounds__(TPB, 3) void out_mfma(
    const short* __restrict__ qt, const short* __restrict__ kt,
    const short* __restrict__ v,
    const float* __restrict__ x, float* __restrict__ out)
{
    const int bg = blockIdx.y;
    const int lane = threadIdx.x & 63, w = threadIdx.x >> 6;
    const int m = lane & 15, g = lane >> 4;

    const short* qtb = qt + (size_t)bg * LSP * HD;
    const short* ktb = kt + (size_t)bg * LSP * HD;
    const short* vb  = v  + (size_t)bg * HD * LSP;

    const int kc0 = blockIdx.x * 128 + 16 * w + m;
    const int kc1 = kc0 + 64;
    const bool real1 = (kc1 < LSP);
    const int kc1c = real1 ? kc1 : (LSP - 1);

    const bf16x8 bk0 = *(const bf16x8*)(ktb + (size_t)kc0  * HD + 8 * g);
    const bf16x8 bk1 = *(const bf16x8*)(ktb + (size_t)kc1c * HD + 8 * g);

    __shared__ unsigned plds[4][2][512];
    unsigned* p0 = &plds[w][0][0];
    unsigned* p1 = &plds[w][1][0];
    const int t2 = 2 * m;            // per-column XOR pattern (even, 16 distinct)
    const int cb = m * 32;

    const f32x4 zero = {0.f, 0.f, 0.f, 0.f};
    f32x4 o00 = zero, o01 = zero, o10 = zero, o11 = zero;

    bf16x8 aq[4];
#pragma unroll
    for (int jt = 0; jt < 4; ++jt)
        aq[jt] = *(const bf16x8*)(qtb + (size_t)(16 * jt + m) * HD + 8 * g);

    for (int j0 = 0; j0 < LSP; j0 += 64) {
        const bf16x8 av0 = *(const bf16x8*)(vb + (size_t)m        * LSP + j0      + 8 * g);
        const bf16x8 av1 = *(const bf16x8*)(vb + (size_t)m        * LSP + j0 + 32 + 8 * g);
        const bf16x8 av2 = *(const bf16x8*)(vb + (size_t)(16 + m) * LSP + j0      + 8 * g);
        const bf16x8 av3 = *(const bf16x8*)(vb + (size_t)(16 + m) * LSP + j0 + 32 + 8 * g);

        const int jn = (j0 + 64 < LSP) ? (j0 + 64) : 0;
#pragma unroll
        for (int jt = 0; jt < 4; ++jt) {
            const f32x4 e0 = __builtin_amdgcn_mfma_f32_16x16x32_bf16(aq[jt], bk0, zero, 0, 0, 0);
            const f32x4 e1 = __builtin_amdgcn_mfma_f32_16x16x32_bf16(aq[jt], bk1, zero, 0, 0, 0);
            aq[jt] = *(const bf16x8*)(qtb + (size_t)(jn + 16 * jt + m) * HD + 8 * g); // prefetch
            uint2v w0, w1;
            w0[0] = pk_bf16(EXP2F(e0[0]), EXP2F(e0[1]));
            w0[1] = pk_bf16(EXP2F(e0[2]), EXP2F(e0[3]));
            w1[0] = pk_bf16(EXP2F(e1[0]), EXP2F(e1[1]));
            w1[1] = pk_bf16(EXP2F(e1[2]), EXP2F(e1[3]));
            const int dws = (8 * jt + 2 * g) ^ t2;    // even -> b64 pair stays contiguous
            *(uint2v*)(p0 + cb + dws) = w0;
            *(uint2v*)(p1 + cb + dws) = w1;
        }

        // B-fragments of P: 2x b64 each, XOR-swizzled addresses (same-wave ordering)
        const int b00 = (4 * g)      ^ t2;
        const int b01 = (4 * g + 2)  ^ t2;
        const int b10 = (16 + 4 * g)     ^ t2;
        const int b11 = (16 + 4 * g + 2) ^ t2;

        U8 bp00, bp01, bp10, bp11;
        bp00.u[0] = *(uint2v*)(p0 + cb + b00); bp00.u[1] = *(uint2v*)(p0 + cb + b01);
        bp01.u[0] = *(uint2v*)(p0 + cb + b10); bp01.u[1] = *(uint2v*)(p0 + cb + b11);
        bp10.u[0] = *(uint2v*)(p1 + cb + b00); bp10.u[1] = *(uint2v*)(p1 + cb + b01);
        bp11.u[0] = *(uint2v*)(p1 + cb + b10); bp11.u[1] = *(uint2v*)(p1 + cb + b11);

        o00 = __builtin_amdgcn_mfma_f32_16x16x32_bf16(av0, bp00.h, o00, 0, 0, 0);
        o00 = __builtin_amdgcn_mfma_f32_16x16x32_bf16(av1, bp01.h, o00, 0, 0, 0);
        o01 = __builtin_amdgcn_mfma_f32_16x16x32_bf16(av2, bp00.h, o01, 0, 0, 0);
        o01 = __builtin_amdgcn_mfma_f32_16x16x32_bf16(av3, bp01.h, o01, 0, 0, 0);
        o10 = __builtin_amdgcn_mfma_f32_16x16x32_bf16(av0, bp10.h, o10, 0, 0, 0);
        o10 = __builtin_amdgcn_mfma_f32_16x16x32_bf16(av1, bp11.h, o10, 0, 0, 0);
        o11 = __builtin_amdgcn_mfma_f32_16x16x32_bf16(av2, bp10.h, o11, 0, 0, 0);
        o11 = __builtin_amdgcn_mfma_f32_16x16x32_bf16(av3, bp11.h, o11, 0, 0, 0);
    }

    const size_t bgb = (size_t)bg * HD * LSP;
#pragma unroll
    for (int r = 0; r < 4; ++r) {
        size_t i0 = bgb + (size_t)(4 * g + r) * LSP + kc0;
        out[i0] = o00[r] + x[i0];
        size_t i1 = bgb + (size_t)(16 + 4 * g + r) * LSP + kc0;
        out[i1] = o01[r] + x[i1];
        if (real1) {
            size_t i2 = bgb + (size_t)(4 * g + r) * LSP + kc1;
            out[i2] = o10[r] + x[i2];
            size_t i3 = bgb + (size_t)(16 + 4 * g + r) * LSP + kc1;
            out[i3] = o11[r] + x[i3];
        }
    }
}

extern "C" void kernel_launch(void* const* d_in, const int* in_sizes, int n_in,
                              void* d_out, int out_size, void* d_ws, size_t ws_size,
                              hipStream_t stream) {
    const float* x  = (const float*)d_in[0];
    const float* Wq = (const float*)d_in[1];
    const float* bq = (const float*)d_in[2];
    const float* Wk = (const float*)d_in[3];
    const float* bk = (const float*)d_in[4];
    const float* Wv = (const float*)d_in[5];
    const float* bv = (const float*)d_in[6];
    float* out = (float*)d_out;

    const size_t QSZ = (size_t)BG * HD * LSP;
    short* qt = (short*)d_ws;
    short* kt = qt + QSZ;
    short* v  = kt + QSZ;

    qkv_mfma<<<dim3(13, BG), TPB, 0, stream>>>(x, Wq, bq, Wk, bk, Wv, bv, qt, kt, v);
    z_mfma  <<<dim3(25, BG), TPB, 0, stream>>>(qt, kt, v);
    out_mfma<<<dim3(25, BG), TPB, 0, stream>>>(qt, kt, v, x, out);
}

// Round 5
// 201.841 us; speedup vs baseline: 1.3280x; 1.3280x over previous
//
#include <hip/hip_runtime.h>

// Problem constants (B=4, C=256, H=W=56, heads=8)
#define NUM_G 8
#define HD    32
#define LSP   3136            // 56*56 = 49*64 exactly
#define BG    32
#define TPB   256
#define LOG2E 1.4426950408889634f

typedef short bf16x8 __attribute__((ext_vector_type(8)));
typedef float f32x4  __attribute__((ext_vector_type(4)));
typedef unsigned uint2v __attribute__((ext_vector_type(2)));
typedef unsigned uint4v __attribute__((ext_vector_type(4)));

union B8 { bf16x8 h; uint4v u; };
union U8 { bf16x8 h; uint2v u[2]; };

#if __has_builtin(__builtin_amdgcn_exp2f)
#define EXP2F __builtin_amdgcn_exp2f
#else
#define EXP2F exp2f
#endif

__device__ __forceinline__ unsigned pk_bf16(float a, float b) {
#if __has_builtin(__builtin_amdgcn_cvt_pk_bf16_f32)
    typedef __bf16 bf16x2_t __attribute__((ext_vector_type(2)));
    bf16x2_t r = __builtin_amdgcn_cvt_pk_bf16_f32(a, b);
    unsigned u; __builtin_memcpy(&u, &r, 4); return u;
#else
    unsigned ua = __float_as_uint(a); ua += 0x7FFFu + ((ua >> 16) & 1u);
    unsigned ub = __float_as_uint(b); ub += 0x7FFFu + ((ub >> 16) & 1u);
    return (ua >> 16) | (ub & 0xFFFF0000u);
#endif
}

__device__ __forceinline__ short f2bf(float f) {
    unsigned u = __float_as_uint(f);
    u += 0x7FFFu + ((u >> 16) & 1u);
    return (short)(u >> 16);
}

__device__ __forceinline__ float bf2f(short s) {
    return __uint_as_float(((unsigned)(unsigned short)s) << 16);
}

// ---------------- Kernel 1: grouped 1x1 conv via MFMA ----------------
__global__ __launch_bounds__(TPB, 4) void qkv_mfma(
    const float* __restrict__ x,
    const float* __restrict__ Wq, const float* __restrict__ bq,
    const float* __restrict__ Wk, const float* __restrict__ bk,
    const float* __restrict__ Wv, const float* __restrict__ bv,
    short* __restrict__ qt, short* __restrict__ kt, short* __restrict__ v)
{
    const int bg = blockIdx.y, gh = bg & (NUM_G - 1);
    const int lane = threadIdx.x & 63, w = threadIdx.x >> 6;
    const int m = lane & 15, g = lane >> 4;

    const float* xb = x + (size_t)bg * HD * LSP;
    short* qtb = qt + (size_t)bg * LSP * HD;
    short* ktb = kt + (size_t)bg * LSP * HD;
    short* vb  = v  + (size_t)bg * HD * LSP;

    B8 wqf[2], wkf[2], wvf[2];
    float bqv[2], bkv[2], bvv[2][4];
#pragma unroll
    for (int h = 0; h < 2; ++h) {
        const int o = 16 * h + m;
        const float* wqp = Wq + (size_t)(gh * HD + o) * HD + 8 * g;
        const float* wkp = Wk + (size_t)(gh * HD + o) * HD + 8 * g;
        const float* wvp = Wv + (size_t)(gh * HD + o) * HD + 8 * g;
#pragma unroll
        for (int p = 0; p < 4; ++p) {
            wqf[h].u[p] = pk_bf16(wqp[2*p] * LOG2E, wqp[2*p+1] * LOG2E);
            wkf[h].u[p] = pk_bf16(wkp[2*p],         wkp[2*p+1]);
            wvf[h].u[p] = pk_bf16(wvp[2*p],         wvp[2*p+1]);
        }
        bqv[h] = bq[gh * HD + o] * LOG2E;
        bkv[h] = bk[gh * HD + o];
#pragma unroll
        for (int r = 0; r < 4; ++r)
            bvv[h][r] = bv[gh * HD + 16 * h + 4 * g + r];
    }

    const int l0 = blockIdx.x * 256 + w * 64;
    const f32x4 zero = {0.f, 0.f, 0.f, 0.f};
#pragma unroll
    for (int c = 0; c < 4; ++c) {
        const int lc = l0 + 16 * c;
        int lrow = lc + m; if (lrow >= LSP) lrow = LSP - 1;
        B8 xf;
#pragma unroll
        for (int p = 0; p < 4; ++p) {
            const float a0 = xb[(size_t)(8*g + 2*p)     * LSP + lrow];
            const float a1 = xb[(size_t)(8*g + 2*p + 1) * LSP + lrow];
            xf.u[p] = pk_bf16(a0, a1);
        }
#pragma unroll
        for (int h = 0; h < 2; ++h) {
            f32x4 cq = __builtin_amdgcn_mfma_f32_16x16x32_bf16(xf.h, wqf[h].h, zero, 0, 0, 0);
            f32x4 ck = __builtin_amdgcn_mfma_f32_16x16x32_bf16(xf.h, wkf[h].h, zero, 0, 0, 0);
            f32x4 cv = __builtin_amdgcn_mfma_f32_16x16x32_bf16(wvf[h].h, xf.h, zero, 0, 0, 0);
            const int lcol = lc + m;
#pragma unroll
            for (int r = 0; r < 4; ++r) {
                const int lr = lc + 4 * g + r;
                if (lr < LSP) {
                    qtb[(size_t)lr * HD + 16 * h + m] = f2bf(cq[r] + bqv[h]);
                    ktb[(size_t)lr * HD + 16 * h + m] = f2bf(ck[r] + bkv[h]);
                }
                if (lcol < LSP)
                    vb[(size_t)(16 * h + 4 * g + r) * LSP + lcol] = f2bf(cv[r] + bvv[h][r]);
            }
        }
    }
}

// ---------------- Kernel 2: Z over 64-j block; v *= 1/Z in-place ----------------
// grid 49x32; waves 4-way split k; per iter: 1 bk load, 4 MFMA, 16 exp.
__global__ __launch_bounds__(TPB, 6) void z_mfma(
    const short* __restrict__ qt, const short* __restrict__ kt,
    short* __restrict__ v)
{
    const int bg = blockIdx.y;
    const int jb = blockIdx.x * 64;
    const int t = threadIdx.x;
    const int lane = t & 63, w = t >> 6, m = lane & 15, g = lane >> 4;

    const short* qtb = qt + (size_t)bg * LSP * HD;
    const short* ktb = kt + (size_t)bg * LSP * HD;
    short* vb = v + (size_t)bg * HD * LSP;

    bf16x8 aq[4];
#pragma unroll
    for (int jq = 0; jq < 4; ++jq)
        aq[jq] = *(const bf16x8*)(qtb + (size_t)(jb + 16 * jq + m) * HD + 8 * g);

    f32x4 zacc[4];
#pragma unroll
    for (int jq = 0; jq < 4; ++jq) zacc[jq] = (f32x4){0.f, 0.f, 0.f, 0.f};

    const f32x4 zero = {0.f, 0.f, 0.f, 0.f};
    for (int it = 0; it < 49; ++it) {
        const bf16x8 bkc = *(const bf16x8*)(ktb + (size_t)(it * 64 + 16 * w + m) * HD + 8 * g);
#pragma unroll
        for (int jq = 0; jq < 4; ++jq) {
            f32x4 c = __builtin_amdgcn_mfma_f32_16x16x32_bf16(aq[jq], bkc, zero, 0, 0, 0);
#pragma unroll
            for (int r = 0; r < 4; ++r) zacc[jq][r] += EXP2F(c[r]);
        }
    }

    __shared__ float zl[64];
    if (t < 64) zl[t] = 0.f;
    __syncthreads();
#pragma unroll
    for (int jq = 0; jq < 4; ++jq) {
#pragma unroll
        for (int r = 0; r < 4; ++r) {
            float s = zacc[jq][r];
            s += __shfl_xor(s, 1); s += __shfl_xor(s, 2);
            s += __shfl_xor(s, 4); s += __shfl_xor(s, 8);
            if (m == 0) atomicAdd(&zl[16 * jq + 4 * g + r], s);
        }
    }
    __syncthreads();

    // scale v rows jb..jb+63: thread t -> d = t>>3, j-chunk = (t&7)*8
    const int d0 = t >> 3;
    const int jl = (t & 7) * 8;
    float rzv[8];
#pragma unroll
    for (int e = 0; e < 8; ++e) rzv[e] = 1.0f / zl[jl + e];
    short* vp = vb + (size_t)d0 * LSP + jb + jl;
    bf16x8 vv = *(bf16x8*)vp;
    B8 o;
#pragma unroll
    for (int p = 0; p < 4; ++p)
        o.u[p] = pk_bf16(bf2f(vv[2*p]) * rzv[2*p], bf2f(vv[2*p+1]) * rzv[2*p+1]);
    *(bf16x8*)vp = o.h;
}

// ---------------- Kernel 3: out[d,k] = sum_j exp2(q'_j.k_k) * v'[d,j] + x ----------------
// grid 49x32 (64 k-cols/block). Wave w sweeps j-tiles {w, w+4, ...}; each wave covers
// all 4 k-subtiles (4x ILP). Cross-wave partial-sum reduction through LDS at the end.
// P transpose via wave-private XOR-swizzled LDS (proved conflict-free in R4).
__global__ __launch_bounds__(TPB, 4) void out_mfma(
    const short* __restrict__ qt, const short* __restrict__ kt,
    const short* __restrict__ v,
    const float* __restrict__ x, float* __restrict__ out)
{
    const int bg = blockIdx.y;
    const int k0 = blockIdx.x * 64;
    const int lane = threadIdx.x & 63, w = threadIdx.x >> 6;
    const int m = lane & 15, g = lane >> 4;

    const short* qtb = qt + (size_t)bg * LSP * HD;
    const short* ktb = kt + (size_t)bg * LSP * HD;
    const short* vb  = v  + (size_t)bg * HD * LSP;

    // B-frags of K: 4 subtiles of 16 cols (exact tiling, no clamps)
    bf16x8 bk[4];
#pragma unroll
    for (int ks = 0; ks < 4; ++ks)
        bk[ks] = *(const bf16x8*)(ktb + (size_t)(k0 + 16 * ks + m) * HD + 8 * g);

    __shared__ unsigned lds[8192];          // 32KB: loop = [w][ks][512]; epilogue = float[4][2048]
    unsigned* pw = lds + w * 2048;
    const int t2 = 2 * m;
    const int cb = m * 32;

    const f32x4 zero = {0.f, 0.f, 0.f, 0.f};
    f32x4 acc[4][2];
#pragma unroll
    for (int ks = 0; ks < 4; ++ks) { acc[ks][0] = zero; acc[ks][1] = zero; }

    for (int jt = w; jt < 49; jt += 4) {
        const int j0 = jt * 64;

        const bf16x8 av0 = *(const bf16x8*)(vb + (size_t)m        * LSP + j0      + 8 * g);
        const bf16x8 av1 = *(const bf16x8*)(vb + (size_t)m        * LSP + j0 + 32 + 8 * g);
        const bf16x8 av2 = *(const bf16x8*)(vb + (size_t)(16 + m) * LSP + j0      + 8 * g);
        const bf16x8 av3 = *(const bf16x8*)(vb + (size_t)(16 + m) * LSP + j0 + 32 + 8 * g);

        bf16x8 aq[4];
#pragma unroll
        for (int jq = 0; jq < 4; ++jq)
            aq[jq] = *(const bf16x8*)(qtb + (size_t)(j0 + 16 * jq + m) * HD + 8 * g);

#pragma unroll
        for (int ks = 0; ks < 4; ++ks) {
#pragma unroll
            for (int jq = 0; jq < 4; ++jq) {
                const f32x4 e = __builtin_amdgcn_mfma_f32_16x16x32_bf16(aq[jq], bk[ks], zero, 0, 0, 0);
                uint2v w0;
                w0[0] = pk_bf16(EXP2F(e[0]), EXP2F(e[1]));
                w0[1] = pk_bf16(EXP2F(e[2]), EXP2F(e[3]));
                *(uint2v*)(pw + ks * 512 + cb + ((8 * jq + 2 * g) ^ t2)) = w0;
            }
        }

        const int blo0 = (4 * g)          ^ t2;
        const int blo1 = (4 * g + 2)      ^ t2;
        const int bhi0 = (16 + 4 * g)     ^ t2;
        const int bhi1 = (16 + 4 * g + 2) ^ t2;
#pragma unroll
        for (int ks = 0; ks < 4; ++ks) {
            U8 bplo, bphi;
            bplo.u[0] = *(uint2v*)(pw + ks * 512 + cb + blo0);
            bplo.u[1] = *(uint2v*)(pw + ks * 512 + cb + blo1);
            bphi.u[0] = *(uint2v*)(pw + ks * 512 + cb + bhi0);
            bphi.u[1] = *(uint2v*)(pw + ks * 512 + cb + bhi1);
            acc[ks][0] = __builtin_amdgcn_mfma_f32_16x16x32_bf16(av0, bplo.h, acc[ks][0], 0, 0, 0);
            acc[ks][0] = __builtin_amdgcn_mfma_f32_16x16x32_bf16(av1, bphi.h, acc[ks][0], 0, 0, 0);
            acc[ks][1] = __builtin_amdgcn_mfma_f32_16x16x32_bf16(av2, bplo.h, acc[ks][1], 0, 0, 0);
            acc[ks][1] = __builtin_amdgcn_mfma_f32_16x16x32_bf16(av3, bphi.h, acc[ks][1], 0, 0, 0);
        }
    }

    // ---- cross-wave reduction of partial out tiles ----
    __syncthreads();                         // all waves done with their P regions
    float* fl = (float*)lds;
#pragma unroll
    for (int ks = 0; ks < 4; ++ks)
#pragma unroll
        for (int ds = 0; ds < 2; ++ds)
#pragma unroll
            for (int r = 0; r < 4; ++r) {
                const int d = 16 * ds + 4 * g + r;
                fl[w * 2048 + d * 64 + 16 * ks + m] = acc[ks][ds][r];
            }
    __syncthreads();

    // thread t: 8 consecutive elements i0 = t*8 of the 32d x 64k tile
    const int t = threadIdx.x;
    const int i0 = t * 8;
    f32x4 s0 = *(f32x4*)(fl + i0);
    f32x4 s1 = *(f32x4*)(fl + i0 + 4);
#pragma unroll
    for (int wi = 1; wi < 4; ++wi) {
        const f32x4 a0 = *(f32x4*)(fl + wi * 2048 + i0);
        const f32x4 a1 = *(f32x4*)(fl + wi * 2048 + i0 + 4);
#pragma unroll
        for (int r = 0; r < 4; ++r) { s0[r] += a0[r]; s1[r] += a1[r]; }
    }
    const int d = t >> 3;
    const int kloc = (t & 7) * 8;
    const size_t idx = (size_t)bg * HD * LSP + (size_t)d * LSP + k0 + kloc;
    const f32x4 x0 = *(const f32x4*)(x + idx);
    const f32x4 x1 = *(const f32x4*)(x + idx + 4);
#pragma unroll
    for (int r = 0; r < 4; ++r) { s0[r] += x0[r]; s1[r] += x1[r]; }
    *(f32x4*)(out + idx)     = s0;
    *(f32x4*)(out + idx + 4) = s1;
}

extern "C" void kernel_launch(void* const* d_in, const int* in_sizes, int n_in,
                              void* d_out, int out_size, void* d_ws, size_t ws_size,
                              hipStream_t stream) {
    const float* x  = (const float*)d_in[0];
    const float* Wq = (const float*)d_in[1];
    const float* bq = (const float*)d_in[2];
    const float* Wk = (const float*)d_in[3];
    const float* bk = (const float*)d_in[4];
    const float* Wv = (const float*)d_in[5];
    const float* bv = (const float*)d_in[6];
    float* out = (float*)d_out;

    const size_t QSZ = (size_t)BG * HD * LSP;
    short* qt = (short*)d_ws;
    short* kt = qt + QSZ;
    short* v  = kt + QSZ;

    qkv_mfma<<<dim3(13, BG), TPB, 0, stream>>>(x, Wq, bq, Wk, bk, Wv, bv, qt, kt, v);
    z_mfma  <<<dim3(49, BG), TPB, 0, stream>>>(qt, kt, v);
    out_mfma<<<dim3(49, BG), TPB, 0, stream>>>(qt, kt, v, x, out);
}